// Round 20
// baseline (304.450 us; speedup 1.0000x reference)
//
#include <hip/hip_runtime.h>
#include <math.h>

#define DD 128          // node embedding dim
#define RR 1024         // root nodes
#define TT 4            // trunk types; encoder TT is the output autoencoder
#define LL 64           // levels
#define MM 2048         // nodes per level
#define NBK 16          // nodes per chunk (one MFMA M-tile)
#define GT 37           // chunk slots per trunk type
#define GO 10           // chunk slots for output type
#define CCAP (4*GT + GO)       // 158 global chunk slots per level == #WGs
#define PAD16 (CCAP*NBK)       // 2528 order slots per level
#define CH CCAP
#define SENTU 0xFFFFFFFFu
#define SENTU8 0xFFFFFFFFFFFFFFFFull

// prep grid-stride work items (64 B each unless noted)
#define ITW1 (5*16*8*64)            // 40960 W1-frag items (16 B each)
#define ITW2 (ITW1 + 5*8*8*64)      // +20480 W2-frag items (16 B each)
#define ITRT (ITW2 + 8192)          // +8192 root-copy items (64 B)
#define ITSN (ITRT + 1048576)       // +1048576 sentinel items (64 B)

typedef __attribute__((ext_vector_type(8))) short short8v;
typedef __attribute__((ext_vector_type(4))) float f32x4;
typedef unsigned long long ull;

static __device__ __forceinline__ unsigned short f2bf(float f) {
    unsigned u = __float_as_uint(f);
    unsigned r = (u + 0x7fffu + ((u >> 16) & 1u)) >> 16;   // RNE
    return (unsigned short)r;
}

// A&S 7.1.26 erf (|err| < 1.5e-7), branchless
static __device__ __forceinline__ float gelu_f(float h) {
    float x  = h * 0.70710678118654752f;
    float ax = fabsf(x);
    float t  = __builtin_amdgcn_rcpf(fmaf(0.3275911f, ax, 1.0f));
    float p  = fmaf(t, 1.061405429f, -1.453152027f);
    p = fmaf(p, t, 1.421413741f);
    p = fmaf(p, t, -0.284496736f);
    p = fmaf(p, t, 0.254829592f);
    p = p * t;
    float er = 1.0f - p * __expf(-ax * ax);
    er = copysignf(er, x);
    return 0.5f * h * (1.0f + er);
}

static __device__ __forceinline__ void st8(void* p, ull v) {
    __hip_atomic_store((ull*)p, v, __ATOMIC_RELAXED, __HIP_MEMORY_SCOPE_AGENT);
}
static __device__ __forceinline__ ull ld8(const void* p) {
    return __hip_atomic_load((const ull*)p, __ATOMIC_RELAXED, __HIP_MEMORY_SCOPE_AGENT);
}

// ---------------------------------------------------------------------------
// ONE cooperative kernel: in-kernel prep (all writes sc1) -> grid barrier
// (r7-proven vmcnt-retire + sc1 counter) -> weights to VGPR -> sentinel-poll
// dataflow level sweep (r19 protocol; 512-thread gather, 2-deep MFMA chains).
// ---------------------------------------------------------------------------
__global__ __launch_bounds__(512, 2) void persist_all(
    const float* __restrict__ root, const float* __restrict__ W1,
    const float* __restrict__ b1, const float* __restrict__ W2,
    const float* __restrict__ b2, const float* __restrict__ slots,
    const int* __restrict__ par, const int* __restrict__ types,
    float* __restrict__ buf,
    unsigned short* __restrict__ W1F, unsigned short* __restrict__ W2F,
    unsigned short* __restrict__ order, int* __restrict__ barmem)
{
    __shared__ int4 descs[LL][NBK];
    __shared__ int ech[LL];
    __shared__ unsigned short axFA[8*64*8];
    __shared__ unsigned short axFB[8*64*8];
    __shared__ unsigned short hxF[8*64*8];
    __shared__ unsigned short order_l[PAD16];
    __shared__ int cnt[10], cur[10];

    int tid = threadIdx.x;
    int wg  = blockIdx.x;
    int e_wg = (wg < 4*GT) ? (wg / GT) : TT;

    // ================= PREP =================
    if (wg < LL) {
        int l = wg;
        if (tid < 10) cnt[tid] = 0;
        __syncthreads();
        for (int s = tid; s < PAD16; s += 512) order_l[s] = 0xFFFFu;
        int thr = RR + (l-1)*MM;
        for (int m = tid; m < MM; m += 512) {
            int gi = l*MM + m;
            int t = types[gi];
            int e = (t >= TT) ? TT : t;
            int p0 = par[2*gi];
            bool rec = (p0 >= RR) && (p0 >= thr);
            if (t < TT) {
                int p1 = par[2*gi + 1];
                rec = rec || ((p1 >= RR) && (p1 >= thr));
            }
            atomicAdd(&cnt[e*2 + (rec ? 1 : 0)], 1);
        }
        __syncthreads();
        if (tid == 0) {
            for (int e = 0; e < 5; e++) {
                int base = ((e < 4) ? e*GT : 4*GT) * NBK;
                int s = cnt[e*2];
                cur[e*2]     = base;
                cur[e*2 + 1] = base + ((s + NBK - 1)/NBK)*NBK;
            }
        }
        __syncthreads();
        for (int m = tid; m < MM; m += 512) {
            int gi = l*MM + m;
            int t = types[gi];
            int e = (t >= TT) ? TT : t;
            int p0 = par[2*gi];
            bool rec = (p0 >= RR) && (p0 >= thr);
            if (t < TT) {
                int p1 = par[2*gi + 1];
                rec = rec || ((p1 >= RR) && (p1 >= thr));
            }
            int pos = atomicAdd(&cur[e*2 + (rec ? 1 : 0)], 1);
            order_l[pos] = (unsigned short)m;
        }
        __syncthreads();
        // write order (sc1, 8B chunks): PAD16*2/8 = 632 ulongs
        const ull* ol = (const ull*)order_l;
        ull* og = (ull*)(order + (size_t)l*PAD16);
        for (int i = tid; i < PAD16/4; i += 512) st8(&og[i], ol[i]);
    }
    // grid-stride shared prep items
    for (long it = (long)wg*512 + tid; it < ITSN; it += (long)CH*512) {
        if (it < ITW1) {
            int t0 = (int)it;
            int lane = t0 & 63;
            int kk = (t0 >> 6) & 7;
            int nt = (t0 >> 9) & 15;
            int e  = t0 >> 13;
            int n  = nt*16 + (lane & 15);
            int k0 = kk*32 + (lane >> 4)*8;
            unsigned short v[8];
            #pragma unroll
            for (int j = 0; j < 8; j++) v[j] = f2bf(W1[(e*256 + k0 + j)*256 + n]);
            ull* d = (ull*)&W1F[(size_t)t0*8];
            st8(&d[0], ((const ull*)v)[0]);
            st8(&d[1], ((const ull*)v)[1]);
        } else if (it < ITW2) {
            int t = (int)(it - ITW1);
            int lane = t & 63;
            int kk = (t >> 6) & 7;
            int nt = (t >> 9) & 7;
            int e  = t >> 12;
            int n  = nt*16 + (lane & 15);
            int k0 = kk*32 + (lane >> 4)*8;
            unsigned short v[8];
            #pragma unroll
            for (int j = 0; j < 8; j++) v[j] = f2bf(W2[(e*256 + k0 + j)*128 + n]);
            ull* d = (ull*)&W2F[(size_t)t*8];
            st8(&d[0], ((const ull*)v)[0]);
            st8(&d[1], ((const ull*)v)[1]);
        } else if (it < ITRT) {
            int i = (int)(it - ITW2);           // 64B root-copy item
            const ull* s = (const ull*)(root + (size_t)i*16);
            ull* d = (ull*)(buf + (size_t)i*16);
            #pragma unroll
            for (int q = 0; q < 8; q++) st8(&d[q], s[q]);
        } else {
            long i = it - ITRT;                 // 64B sentinel item
            ull* d = (ull*)(buf + (size_t)RR*DD + i*16);
            #pragma unroll
            for (int q = 0; q < 8; q++) st8(&d[q], SENTU8);
        }
    }
    // ---- grid barrier: all sc1 prep stores retired => at L3 ----
    asm volatile("s_waitcnt vmcnt(0)" ::: "memory");
    __syncthreads();
    if (tid == 0) {
        int old = __hip_atomic_fetch_add(barmem, 1, __ATOMIC_RELAXED, __HIP_MEMORY_SCOPE_AGENT);
        if (old == CH - 1) {
            __hip_atomic_store(barmem + 32, 1, __ATOMIC_RELAXED, __HIP_MEMORY_SCOPE_AGENT);
        } else {
            while (__hip_atomic_load(barmem + 32, __ATOMIC_RELAXED, __HIP_MEMORY_SCOPE_AGENT) == 0)
                __builtin_amdgcn_s_sleep(2);
        }
    }
    __syncthreads();

    // ================= LEVEL SWEEP =================
    int w  = tid >> 6;        // wave 0..7
    int lq = tid & 63;        // lane
    int m_own   = tid >> 5;   // node 0..15 (32B gather units)
    int hs      = tid & 31;   // half-seg 0..31
    int kk_own  = hs >> 2;
    int lane_own = m_own + 16*(hs & 3);
    int seg16   = hs >> 1;    // 16-float segment 0..15
    int half8   = hs & 1;     // which 8-float half

    // weight B-fragments + biases (plain cached reads; L2 clean, sources sc1)
    short8v w1r0[8], w1r1[8], w2r[8];
    #pragma unroll
    for (int kk = 0; kk < 8; kk++) {
        w1r0[kk] = *(const short8v*)&W1F[(((e_wg*16 + 2*w + 0)*8 + kk)*64 + lq)*8];
        w1r1[kk] = *(const short8v*)&W1F[(((e_wg*16 + 2*w + 1)*8 + kk)*64 + lq)*8];
        w2r[kk]  = *(const short8v*)&W2F[(((e_wg*8  + w)*8 + kk)*64 + lq)*8];
    }
    float b1v0 = b1[e_wg*256 + (2*w + 0)*16 + (lq & 15)];
    float b1v1 = b1[e_wg*256 + (2*w + 1)*16 + (lq & 15)];
    float b2v  = b2[e_wg*128 + w*16 + (lq & 15)];

    // resolve all levels' descriptors
    for (int i = tid; i < LL*NBK; i += 512) {
        int l = i >> 4, s = i & 15;
        unsigned short o = order[(size_t)l*PAD16 + wg*NBK + s];
        int4 d;
        if (o == 0xFFFFu) {
            d = make_int4(-1, 0, 0, -1);
        } else {
            int gi = l*MM + (int)o;
            int t = types[gi];
            int e = (t >= TT) ? TT : t;
            int p0 = par[2*gi];
            int p1 = (t >= TT) ? ~(t - TT) : par[2*gi + 1];
            d = make_int4((int)o, p0, p1, e);
        }
        descs[l][s] = d;
    }
    __syncthreads();
    for (int i = tid; i < LL; i += 512) ech[i] = descs[i][0].w;
    __syncthreads();

    #define RESOLVE_SRC(l1, S, P) {                                            \
        int4 d_ = descs[l1][m_own];                                            \
        if (d_.x < 0) { P = true; S = nullptr; }                               \
        else {                                                                 \
            P = false;                                                         \
            if (seg16 < 8)     S = buf + (size_t)d_.y*DD + seg16*16 + half8*8; \
            else if (d_.z < 0) S = slots + (size_t)(~d_.z)*DD + (seg16-8)*16 + half8*8; \
            else               S = buf + (size_t)d_.z*DD + (seg16-8)*16 + half8*8; \
        } }

    #define LOAD4P(S, U) {                                                     \
        const ull* s8_ = (const ull*)(S);                                      \
        _Pragma("unroll")                                                      \
        for (int q_ = 0; q_ < 4; q_++) U[q_] = s8_[q_];                        \
    }
    #define LOAD4(S, U) {                                                      \
        const ull* s8_ = (const ull*)(S);                                      \
        _Pragma("unroll")                                                      \
        for (int q_ = 0; q_ < 4; q_++) U[q_] = ld8(&s8_[q_]);                  \
    }
    #define VERIFY4(U, OK) { OK = true;                                        \
        _Pragma("unroll")                                                      \
        for (int q_ = 0; q_ < 4; q_++) {                                       \
            unsigned lo_ = (unsigned)U[q_], hi_ = (unsigned)(U[q_] >> 32);     \
            OK = OK && (lo_ != SENTU) && (hi_ != SENTU);                       \
        } }
    #define WRITE_FRAG1(AXT, U) {                                              \
        unsigned short t_[8];                                                  \
        _Pragma("unroll")                                                      \
        for (int q_ = 0; q_ < 4; q_++) {                                       \
            t_[2*q_]   = f2bf(__uint_as_float((unsigned)U[q_]));               \
            t_[2*q_+1] = f2bf(__uint_as_float((unsigned)(U[q_] >> 32)));       \
        }                                                                      \
        *(short8v*)&AXT[(kk_own*64 + lane_own)*8] = *(short8v*)t_;             \
    }

    // level-0 gather (roots/slots: clean)
    {
        const float* src; bool pad;
        RESOLVE_SRC(0, src, pad);
        ull u0[4];
        if (!pad) {
            LOAD4P(src, u0);
            bool ok; VERIFY4(u0, ok);
            while (!ok) { __builtin_amdgcn_s_sleep(1); LOAD4(src, u0); VERIFY4(u0, ok); }
        } else {
            #pragma unroll
            for (int q = 0; q < 4; q++) u0[q] = 0ull;
        }
        WRITE_FRAG1(axFA, u0);
    }
    __syncthreads();

    unsigned short* axc = axFA;
    unsigned short* axn = axFB;

    for (int l = 0; l < LL; l++) {
        bool havN = (l + 1 < LL);

        // phase A: plain loads for next level's parents
        const float* srcN = nullptr; bool padN = true; bool ok = true;
        ull u[4];
        #pragma unroll
        for (int q = 0; q < 4; q++) u[q] = 0ull;
        if (havN) {
            RESOLVE_SRC(l+1, srcN, padN);
            if (!padN) { LOAD4P(srcN, u); ok = false; }
        }
        __builtin_amdgcn_sched_barrier(0);

        int e = ech[l];
        if (e >= 0) {
            // layer 1: 4 chains of depth 2 per tile
            f32x4 z4 = (f32x4){0.f,0.f,0.f,0.f};
            f32x4 a00 = (f32x4){b1v0,b1v0,b1v0,b1v0}, a01 = z4, a02 = z4, a03 = z4;
            f32x4 a10 = (f32x4){b1v1,b1v1,b1v1,b1v1}, a11 = z4, a12 = z4, a13 = z4;
            {
                const short8v* Ab = (const short8v*)axc;
                short8v a0 = Ab[0*64+lq], a1 = Ab[1*64+lq], a2 = Ab[2*64+lq], a3 = Ab[3*64+lq];
                short8v a4 = Ab[4*64+lq], a5 = Ab[5*64+lq], a6 = Ab[6*64+lq], a7 = Ab[7*64+lq];
                a00 = __builtin_amdgcn_mfma_f32_16x16x32_bf16(a0, w1r0[0], a00, 0,0,0);
                a01 = __builtin_amdgcn_mfma_f32_16x16x32_bf16(a2, w1r0[2], a01, 0,0,0);
                a02 = __builtin_amdgcn_mfma_f32_16x16x32_bf16(a4, w1r0[4], a02, 0,0,0);
                a03 = __builtin_amdgcn_mfma_f32_16x16x32_bf16(a6, w1r0[6], a03, 0,0,0);
                a10 = __builtin_amdgcn_mfma_f32_16x16x32_bf16(a0, w1r1[0], a10, 0,0,0);
                a11 = __builtin_amdgcn_mfma_f32_16x16x32_bf16(a2, w1r1[2], a11, 0,0,0);
                a12 = __builtin_amdgcn_mfma_f32_16x16x32_bf16(a4, w1r1[4], a12, 0,0,0);
                a13 = __builtin_amdgcn_mfma_f32_16x16x32_bf16(a6, w1r1[6], a13, 0,0,0);
                a00 = __builtin_amdgcn_mfma_f32_16x16x32_bf16(a1, w1r0[1], a00, 0,0,0);
                a01 = __builtin_amdgcn_mfma_f32_16x16x32_bf16(a3, w1r0[3], a01, 0,0,0);
                a02 = __builtin_amdgcn_mfma_f32_16x16x32_bf16(a5, w1r0[5], a02, 0,0,0);
                a03 = __builtin_amdgcn_mfma_f32_16x16x32_bf16(a7, w1r0[7], a03, 0,0,0);
                a10 = __builtin_amdgcn_mfma_f32_16x16x32_bf16(a1, w1r1[1], a10, 0,0,0);
                a11 = __builtin_amdgcn_mfma_f32_16x16x32_bf16(a3, w1r1[3], a11, 0,0,0);
                a12 = __builtin_amdgcn_mfma_f32_16x16x32_bf16(a5, w1r1[5], a12, 0,0,0);
                a13 = __builtin_amdgcn_mfma_f32_16x16x32_bf16(a7, w1r1[7], a13, 0,0,0);
            }
            f32x4 acc0 = (a00 + a01) + (a02 + a03);
            f32x4 acc1 = (a10 + a11) + (a12 + a13);
            // check A: arrived? else sc1 reissue (hidden under GELU/L2)
            if (havN && !padN && !ok) {
                VERIFY4(u, ok);
                if (!ok) LOAD4(srcN, u);
            }
            __builtin_amdgcn_sched_barrier(0);

            // GELU + scatter H
            #pragma unroll
            for (int c = 0; c < 2; c++) {
                int nh = (2*w + c)*16 + (lq & 15);
                int kk2 = nh >> 5;
                int jj  = nh & 7;
                int lhi = 16*((nh >> 3) & 3);
                #pragma unroll
                for (int r = 0; r < 4; r++) {
                    int m = (lq >> 4)*4 + r;
                    float h = (c == 0) ? acc0[r] : acc1[r];
                    hxF[(kk2*64 + (m + lhi))*8 + jj] = f2bf(gelu_f(h));
                }
            }
            __syncthreads();

            // layer 2: 4 chains of depth 2
            f32x4 z4b = (f32x4){0.f,0.f,0.f,0.f};
            f32x4 c0 = (f32x4){b2v,b2v,b2v,b2v}, c1 = z4b, c2 = z4b, c3 = z4b;
            {
                const short8v* Hb = (const short8v*)hxF;
                short8v h0 = Hb[0*64+lq], h1 = Hb[1*64+lq], h2 = Hb[2*64+lq], h3 = Hb[3*64+lq];
                short8v h4 = Hb[4*64+lq], h5 = Hb[5*64+lq], h6 = Hb[6*64+lq], h7 = Hb[7*64+lq];
                c0 = __builtin_amdgcn_mfma_f32_16x16x32_bf16(h0, w2r[0], c0, 0,0,0);
                c1 = __builtin_amdgcn_mfma_f32_16x16x32_bf16(h2, w2r[2], c1, 0,0,0);
                c2 = __builtin_amdgcn_mfma_f32_16x16x32_bf16(h4, w2r[4], c2, 0,0,0);
                c3 = __builtin_amdgcn_mfma_f32_16x16x32_bf16(h6, w2r[6], c3, 0,0,0);
                c0 = __builtin_amdgcn_mfma_f32_16x16x32_bf16(h1, w2r[1], c0, 0,0,0);
                c1 = __builtin_amdgcn_mfma_f32_16x16x32_bf16(h3, w2r[3], c1, 0,0,0);
                c2 = __builtin_amdgcn_mfma_f32_16x16x32_bf16(h5, w2r[5], c2, 0,0,0);
                c3 = __builtin_amdgcn_mfma_f32_16x16x32_bf16(h7, w2r[7], c3, 0,0,0);
            }
            f32x4 acc2 = (c0 + c1) + (c2 + c3);
            // result rows: sc1 fire-and-forget
            int baserow = RR + l*MM;
            int n = w*16 + (lq & 15);
            #pragma unroll
            for (int r = 0; r < 4; r++) {
                int m = (lq >> 4)*4 + r;
                int node = descs[l][m].x;
                if (node >= 0)
                    __hip_atomic_store(&buf[(size_t)(baserow + node)*DD + n], acc2[r],
                                       __ATOMIC_RELAXED, __HIP_MEMORY_SCOPE_AGENT);
            }
            // check B: rides the store window
            if (havN && !padN && !ok) {
                VERIFY4(u, ok);
                if (!ok) LOAD4(srcN, u);
            }
        }

        // phase B: spin (sc1) only on genuine still-pending parents
        if (havN) {
            if (!padN) {
                while (!ok) {
                    VERIFY4(u, ok);
                    if (!ok) { __builtin_amdgcn_s_sleep(1); LOAD4(srcN, u); }
                }
            }
            WRITE_FRAG1(axn, u);
        }

        __syncthreads();
        unsigned short* t2 = axc; axc = axn; axn = t2;
    }
}

extern "C" void kernel_launch(void* const* d_in, const int* in_sizes, int n_in,
                              void* d_out, int out_size, void* d_ws, size_t ws_size,
                              hipStream_t stream) {
    const float* root  = (const float*)d_in[0];   // (1024, 128)
    const float* W1    = (const float*)d_in[1];   // (5, 256, 256)
    const float* b1    = (const float*)d_in[2];   // (5, 256)
    const float* W2    = (const float*)d_in[3];   // (5, 256, 128)
    const float* b2    = (const float*)d_in[4];   // (5, 128)
    const float* slots = (const float*)d_in[5];   // (256, 128)
    const int*   par   = (const int*)d_in[6];     // (131072, 2)
    const int*   typ   = (const int*)d_in[7];     // (131072,)
    float* out = (float*)d_out;                   // (132096, 128)

    unsigned short* W1F   = (unsigned short*)d_ws;          // 327680 shorts
    unsigned short* W2F   = W1F + 5*16*8*64*8;              // 163840 shorts
    unsigned short* order = W2F + 5*8*8*64*8;               // 64*2528 shorts
    int* barmem = (int*)(order + (size_t)LL*PAD16);         // 64 ints

    hipMemsetAsync(barmem, 0, 64*sizeof(int), stream);

    void* args[] = { (void*)&root, (void*)&W1, (void*)&b1, (void*)&W2,
                     (void*)&b2, (void*)&slots, (void*)&par, (void*)&typ,
                     (void*)&out, (void*)&W1F, (void*)&W2F, (void*)&order,
                     (void*)&barmem };
    hipLaunchCooperativeKernel((const void*)persist_all, dim3(CH), dim3(512),
                               args, 0, stream);
}

// Round 21
// 213.728 us; speedup vs baseline: 1.4245x; 1.4245x over previous
//
#include <hip/hip_runtime.h>
#include <math.h>

#define DD 128          // node embedding dim
#define RR 1024         // root nodes
#define TT 4            // trunk types; encoder TT is the output autoencoder
#define LL 64           // levels
#define MM 2048         // nodes per level
#define NBK 16          // nodes per chunk (one MFMA M-tile)
#define GT 37           // chunk slots per trunk type
#define GO 10           // chunk slots for output type
#define CCAP (4*GT + GO)       // 158 global chunk slots per level == #WGs
#define PAD16 (CCAP*NBK)       // 2528 order slots per level
#define CH CCAP
#define SENTU 0xFFFFFFFFu      // NaN sentinel; MLP outputs are finite -> never equal

typedef __attribute__((ext_vector_type(8))) short short8v;
typedef __attribute__((ext_vector_type(4))) float f32x4;
typedef unsigned long long ull;

static __device__ __forceinline__ unsigned short f2bf(float f) {
    unsigned u = __float_as_uint(f);
    unsigned r = (u + 0x7fffu + ((u >> 16) & 1u)) >> 16;   // RNE
    return (unsigned short)r;
}

// A&S 7.1.26 erf (|err| < 1.5e-7), branchless
static __device__ __forceinline__ float gelu_f(float h) {
    float x  = h * 0.70710678118654752f;
    float ax = fabsf(x);
    float t  = __builtin_amdgcn_rcpf(fmaf(0.3275911f, ax, 1.0f));
    float p  = fmaf(t, 1.061405429f, -1.453152027f);
    p = fmaf(p, t, 1.421413741f);
    p = fmaf(p, t, -0.284496736f);
    p = fmaf(p, t, 0.254829592f);
    p = p * t;
    float er = 1.0f - p * __expf(-ax * ax);
    er = copysignf(er, x);
    return 0.5f * h * (1.0f + er);
}

// ---------------------------------------------------------------------------
// Fused prep (r17/r19): order build | weight convert | root copy | sentinel
// fill. All PLAIN cached stores (L2 write-back absorbs the bulk traffic) --
// published to L3 by the dispatch boundary before the persistent kernel.
// ---------------------------------------------------------------------------
__global__ __launch_bounds__(256) void prep_all(
    const float* __restrict__ root, const float* __restrict__ W1,
    const float* __restrict__ W2, const int* __restrict__ types,
    const int* __restrict__ par,
    float* __restrict__ buf,
    unsigned short* __restrict__ W1F, unsigned short* __restrict__ W2F,
    unsigned short* __restrict__ order)
{
    int bid = blockIdx.x, tid = threadIdx.x;
    if (bid < LL) {
        int l = bid;
        __shared__ int cnt[10], cur[10];
        if (tid < 10) cnt[tid] = 0;
        __syncthreads();
        for (int s = tid; s < PAD16; s += 256) order[l*PAD16 + s] = 0xFFFFu;
        int thr = RR + (l-1)*MM;    // parents >= thr come from level l-1
        for (int m = tid; m < MM; m += 256) {
            int gi = l*MM + m;
            int t = types[gi];
            int e = (t >= TT) ? TT : t;
            int p0 = par[2*gi];
            bool rec = (p0 >= RR) && (p0 >= thr);
            if (t < TT) {
                int p1 = par[2*gi + 1];
                rec = rec || ((p1 >= RR) && (p1 >= thr));
            }
            atomicAdd(&cnt[e*2 + (rec ? 1 : 0)], 1);
        }
        __syncthreads();
        if (tid == 0) {
            for (int e = 0; e < 5; e++) {
                int base = ((e < 4) ? e*GT : 4*GT) * NBK;
                int s = cnt[e*2];
                cur[e*2]     = base;
                cur[e*2 + 1] = base + ((s + NBK - 1)/NBK)*NBK;
            }
        }
        __syncthreads();
        for (int m = tid; m < MM; m += 256) {
            int gi = l*MM + m;
            int t = types[gi];
            int e = (t >= TT) ? TT : t;
            int p0 = par[2*gi];
            bool rec = (p0 >= RR) && (p0 >= thr);
            if (t < TT) {
                int p1 = par[2*gi + 1];
                rec = rec || ((p1 >= RR) && (p1 >= thr));
            }
            int pos = atomicAdd(&cur[e*2 + (rec ? 1 : 0)], 1);
            order[l*PAD16 + pos] = (unsigned short)m;
        }
    } else if (bid < LL + 240) {
        int t0 = (bid - LL)*256 + tid;
        if (t0 < 5*16*8*64) {
            int lane = t0 & 63;
            int kk = (t0 >> 6) & 7;
            int nt = (t0 >> 9) & 15;
            int e  = t0 >> 13;
            int n  = nt*16 + (lane & 15);
            int k0 = kk*32 + (lane >> 4)*8;
            unsigned short v[8];
            #pragma unroll
            for (int j = 0; j < 8; j++) v[j] = f2bf(W1[(e*256 + k0 + j)*256 + n]);
            *(short8v*)&W1F[t0*8] = *(short8v*)v;
        } else {
            int t = t0 - 5*16*8*64;   // < 20480
            int lane = t & 63;
            int kk = (t >> 6) & 7;
            int nt = (t >> 9) & 7;
            int e  = t >> 12;
            int n  = nt*16 + (lane & 15);
            int k0 = kk*32 + (lane >> 4)*8;
            unsigned short v[8];
            #pragma unroll
            for (int j = 0; j < 8; j++) v[j] = f2bf(W2[(e*256 + k0 + j)*128 + n]);
            *(short8v*)&W2F[t*8] = *(short8v*)v;
        }
    } else if (bid < LL + 240 + 32) {
        int idx = (bid - (LL + 240))*256 + tid;   // 0..8191
        const f32x4* r4 = (const f32x4*)root;
        f32x4* o4 = (f32x4*)buf;
        #pragma unroll
        for (int q = 0; q < 4; q++) o4[idx*4 + q] = r4[idx*4 + q];
    } else {
        // sentinel fill: rows RR..N-1, 16 floats per thread
        int idx = (bid - (LL + 240 + 32))*256 + tid;   // 0 .. 1048575
        float s = __uint_as_float(SENTU);
        f32x4 sv = (f32x4){s, s, s, s};
        f32x4* p = (f32x4*)(buf + (size_t)RR*DD) + (size_t)idx*4;
        p[0] = sv; p[1] = sv; p[2] = sv; p[3] = sv;
    }
}

// ---------------------------------------------------------------------------
// Persistent dataflow kernel (r19 + 512-thread gather + 2-deep MFMA chains):
// CCAP WGs x 512 threads (8 waves). Static encoder type per WG; weights in
// VGPRs. Sentinel-poll protocol: phase-A gather loads PLAIN CACHED (L2 clean
// at dispatch; buf rows only ever written via sc1 -> plain load returns real
// value or sentinel, never stale); sentinel-misses fall back to sc1
// reload/spin. Producers fire sc1 stores -- no drain, no flag.
// ---------------------------------------------------------------------------
__global__ __launch_bounds__(512, 2) void persist_mfma(
    const unsigned short* __restrict__ W1F, const unsigned short* __restrict__ W2F,
    const float* __restrict__ b1, const float* __restrict__ b2,
    const float* __restrict__ slots, const int* __restrict__ par,
    const int* __restrict__ types, const unsigned short* __restrict__ order,
    float* __restrict__ buf)
{
    __shared__ int4 descs[LL][NBK];            // {node, p0, p1(~slot if out), etype}
    __shared__ int ech[LL];
    __shared__ unsigned short axFA[8*64*8];    // A-frags of x, 8 KB
    __shared__ unsigned short axFB[8*64*8];    // double buffer, 8 KB
    __shared__ unsigned short hxF[8*64*8];     // A-frags of h, 8 KB

    int tid = threadIdx.x;
    int wg  = blockIdx.x;
    int e_wg = (wg < 4*GT) ? (wg / GT) : TT;   // static encoder type of this WG

    int w  = tid >> 6;    // wave 0..7
    int lq = tid & 63;    // lane
    // 512-thread gather: each thread owns 32 B (8 floats) = one A-fragment
    int m_own    = tid >> 5;          // node 0..15
    int hs       = tid & 31;          // 8-float slot 0..31 (k = hs*8)
    int kk_own   = hs >> 2;           // fragment kk
    int lane_own = m_own + 16*(hs & 3);
    int seg16    = hs >> 1;           // 16-float segment 0..15
    int half8    = hs & 1;            // which 8-float half

    // ---- preload weight B-fragments + biases into registers ----
    short8v w1r0[8], w1r1[8], w2r[8];
    #pragma unroll
    for (int kk = 0; kk < 8; kk++) {
        w1r0[kk] = *(const short8v*)&W1F[(((e_wg*16 + 2*w + 0)*8 + kk)*64 + lq)*8];
        w1r1[kk] = *(const short8v*)&W1F[(((e_wg*16 + 2*w + 1)*8 + kk)*64 + lq)*8];
        w2r[kk]  = *(const short8v*)&W2F[(((e_wg*8  + w)*8 + kk)*64 + lq)*8];
    }
    float b1v0 = b1[e_wg*256 + (2*w + 0)*16 + (lq & 15)];
    float b1v1 = b1[e_wg*256 + (2*w + 1)*16 + (lq & 15)];
    float b2v  = b2[e_wg*128 + w*16 + (lq & 15)];

    // ---- prologue: resolve all levels' descriptors ----
    for (int i = tid; i < LL*NBK; i += 512) {
        int l = i >> 4, s = i & 15;
        unsigned short o = order[l*PAD16 + wg*NBK + s];
        int4 d;
        if (o == 0xFFFFu) {
            d = make_int4(-1, 0, 0, -1);
        } else {
            int gi = l*MM + (int)o;
            int t = types[gi];
            int e = (t >= TT) ? TT : t;
            int p0 = par[2*gi];
            int p1 = (t >= TT) ? ~(t - TT) : par[2*gi + 1];
            d = make_int4((int)o, p0, p1, e);
        }
        descs[l][s] = d;
    }
    __syncthreads();
    for (int i = tid; i < LL; i += 512) ech[i] = descs[i][0].w;
    __syncthreads();

    #define RESOLVE_SRC(l1, S, P) {                                            \
        int4 d_ = descs[l1][m_own];                                            \
        if (d_.x < 0) { P = true; S = nullptr; }                               \
        else {                                                                 \
            P = false;                                                         \
            if (seg16 < 8)     S = buf + (size_t)d_.y*DD + seg16*16 + half8*8; \
            else if (d_.z < 0) S = slots + (size_t)(~d_.z)*DD + (seg16-8)*16 + half8*8; \
            else               S = buf + (size_t)d_.z*DD + (seg16-8)*16 + half8*8; \
        } }

    // plain cached loads (fast path; may return sentinel if not yet landed)
    #define LOAD4P(S, U) {                                                     \
        const ull* s8_ = (const ull*)(S);                                      \
        _Pragma("unroll")                                                      \
        for (int q_ = 0; q_ < 4; q_++) U[q_] = s8_[q_];                        \
    }
    // sc1 L2-bypass loads (truth path for pending parents)
    #define LOAD4(S, U) {                                                      \
        const ull* s8_ = (const ull*)(S);                                      \
        _Pragma("unroll")                                                      \
        for (int q_ = 0; q_ < 4; q_++)                                         \
            U[q_] = __hip_atomic_load(&s8_[q_], __ATOMIC_RELAXED,              \
                                      __HIP_MEMORY_SCOPE_AGENT);               \
    }
    #define VERIFY4(U, OK) { OK = true;                                        \
        _Pragma("unroll")                                                      \
        for (int q_ = 0; q_ < 4; q_++) {                                       \
            unsigned lo_ = (unsigned)U[q_], hi_ = (unsigned)(U[q_] >> 32);     \
            OK = OK && (lo_ != SENTU) && (hi_ != SENTU);                       \
        } }
    #define WRITE_FRAG1(AXT, U) {                                              \
        unsigned short t_[8];                                                  \
        _Pragma("unroll")                                                      \
        for (int q_ = 0; q_ < 4; q_++) {                                       \
            t_[2*q_]   = f2bf(__uint_as_float((unsigned)U[q_]));               \
            t_[2*q_+1] = f2bf(__uint_as_float((unsigned)(U[q_] >> 32)));       \
        }                                                                      \
        *(short8v*)&AXT[(kk_own*64 + lane_own)*8] = *(short8v*)t_;             \
    }

    // ---- level-0 gather (roots/slots: written by prep, always clean) ----
    {
        const float* src; bool pad;
        RESOLVE_SRC(0, src, pad);
        ull u0[4];
        if (!pad) {
            LOAD4P(src, u0);
            bool ok; VERIFY4(u0, ok);
            while (!ok) { __builtin_amdgcn_s_sleep(1); LOAD4(src, u0); VERIFY4(u0, ok); }
        } else {
            #pragma unroll
            for (int q = 0; q < 4; q++) u0[q] = 0ull;
        }
        WRITE_FRAG1(axFA, u0);
    }
    __syncthreads();

    unsigned short* axc = axFA;
    unsigned short* axn = axFB;

    for (int l = 0; l < LL; l++) {
        bool havN = (l + 1 < LL);

        // ---- phase A: issue PLAIN loads for level l+1 parents ----
        const float* srcN = nullptr; bool padN = true; bool ok = true;
        ull u[4];
        #pragma unroll
        for (int q = 0; q < 4; q++) u[q] = 0ull;
        if (havN) {
            RESOLVE_SRC(l+1, srcN, padN);
            if (!padN) { LOAD4P(srcN, u); ok = false; }
        }
        __builtin_amdgcn_sched_barrier(0);   // pin: loads issued before compute

        int e = ech[l];
        if (e >= 0) {
            // ---- layer 1: H = GELU(X @ W1 + b1), 4 chains of depth 2 ----
            f32x4 z4 = (f32x4){0.f,0.f,0.f,0.f};
            f32x4 a00 = (f32x4){b1v0,b1v0,b1v0,b1v0}, a01 = z4, a02 = z4, a03 = z4;
            f32x4 a10 = (f32x4){b1v1,b1v1,b1v1,b1v1}, a11 = z4, a12 = z4, a13 = z4;
            {
                const short8v* Ab = (const short8v*)axc;
                short8v a0 = Ab[0*64+lq], a1 = Ab[1*64+lq], a2 = Ab[2*64+lq], a3 = Ab[3*64+lq];
                short8v a4 = Ab[4*64+lq], a5 = Ab[5*64+lq], a6 = Ab[6*64+lq], a7 = Ab[7*64+lq];
                a00 = __builtin_amdgcn_mfma_f32_16x16x32_bf16(a0, w1r0[0], a00, 0,0,0);
                a01 = __builtin_amdgcn_mfma_f32_16x16x32_bf16(a2, w1r0[2], a01, 0,0,0);
                a02 = __builtin_amdgcn_mfma_f32_16x16x32_bf16(a4, w1r0[4], a02, 0,0,0);
                a03 = __builtin_amdgcn_mfma_f32_16x16x32_bf16(a6, w1r0[6], a03, 0,0,0);
                a10 = __builtin_amdgcn_mfma_f32_16x16x32_bf16(a0, w1r1[0], a10, 0,0,0);
                a11 = __builtin_amdgcn_mfma_f32_16x16x32_bf16(a2, w1r1[2], a11, 0,0,0);
                a12 = __builtin_amdgcn_mfma_f32_16x16x32_bf16(a4, w1r1[4], a12, 0,0,0);
                a13 = __builtin_amdgcn_mfma_f32_16x16x32_bf16(a6, w1r1[6], a13, 0,0,0);
                a00 = __builtin_amdgcn_mfma_f32_16x16x32_bf16(a1, w1r0[1], a00, 0,0,0);
                a01 = __builtin_amdgcn_mfma_f32_16x16x32_bf16(a3, w1r0[3], a01, 0,0,0);
                a02 = __builtin_amdgcn_mfma_f32_16x16x32_bf16(a5, w1r0[5], a02, 0,0,0);
                a03 = __builtin_amdgcn_mfma_f32_16x16x32_bf16(a7, w1r0[7], a03, 0,0,0);
                a10 = __builtin_amdgcn_mfma_f32_16x16x32_bf16(a1, w1r1[1], a10, 0,0,0);
                a11 = __builtin_amdgcn_mfma_f32_16x16x32_bf16(a3, w1r1[3], a11, 0,0,0);
                a12 = __builtin_amdgcn_mfma_f32_16x16x32_bf16(a5, w1r1[5], a12, 0,0,0);
                a13 = __builtin_amdgcn_mfma_f32_16x16x32_bf16(a7, w1r1[7], a13, 0,0,0);
            }
            f32x4 acc0 = (a00 + a01) + (a02 + a03);
            f32x4 acc1 = (a10 + a11) + (a12 + a13);
            // ---- check A: arrived? else sc1 reissue (hidden) ----
            if (havN && !padN && !ok) {
                VERIFY4(u, ok);
                if (!ok) LOAD4(srcN, u);
            }
            __builtin_amdgcn_sched_barrier(0);

            // GELU + scatter H into A-frag LDS (nt = 2w+c, c in {0,1})
            #pragma unroll
            for (int c = 0; c < 2; c++) {
                int nh = (2*w + c)*16 + (lq & 15);
                int kk2 = nh >> 5;
                int jj  = nh & 7;
                int lhi = 16*((nh >> 3) & 3);
                #pragma unroll
                for (int r = 0; r < 4; r++) {
                    int m = (lq >> 4)*4 + r;
                    float h = (c == 0) ? acc0[r] : acc1[r];
                    hxF[(kk2*64 + (m + lhi))*8 + jj] = f2bf(gelu_f(h));
                }
            }
            __syncthreads();

            // ---- layer 2: OUT = H @ W2 + b2, 4 chains of depth 2 ----
            f32x4 z4b = (f32x4){0.f,0.f,0.f,0.f};
            f32x4 c0 = (f32x4){b2v,b2v,b2v,b2v}, c1 = z4b, c2 = z4b, c3 = z4b;
            {
                const short8v* Hb = (const short8v*)hxF;
                short8v h0 = Hb[0*64+lq], h1 = Hb[1*64+lq], h2 = Hb[2*64+lq], h3 = Hb[3*64+lq];
                short8v h4 = Hb[4*64+lq], h5 = Hb[5*64+lq], h6 = Hb[6*64+lq], h7 = Hb[7*64+lq];
                c0 = __builtin_amdgcn_mfma_f32_16x16x32_bf16(h0, w2r[0], c0, 0,0,0);
                c1 = __builtin_amdgcn_mfma_f32_16x16x32_bf16(h2, w2r[2], c1, 0,0,0);
                c2 = __builtin_amdgcn_mfma_f32_16x16x32_bf16(h4, w2r[4], c2, 0,0,0);
                c3 = __builtin_amdgcn_mfma_f32_16x16x32_bf16(h6, w2r[6], c3, 0,0,0);
                c0 = __builtin_amdgcn_mfma_f32_16x16x32_bf16(h1, w2r[1], c0, 0,0,0);
                c1 = __builtin_amdgcn_mfma_f32_16x16x32_bf16(h3, w2r[3], c1, 0,0,0);
                c2 = __builtin_amdgcn_mfma_f32_16x16x32_bf16(h5, w2r[5], c2, 0,0,0);
                c3 = __builtin_amdgcn_mfma_f32_16x16x32_bf16(h7, w2r[7], c3, 0,0,0);
            }
            f32x4 acc2 = (c0 + c1) + (c2 + c3);
            // result rows: sc1 write-through; fire-and-forget
            int baserow = RR + l*MM;
            int n = w*16 + (lq & 15);
            #pragma unroll
            for (int r = 0; r < 4; r++) {
                int m = (lq >> 4)*4 + r;
                int node = descs[l][m].x;
                if (node >= 0)
                    __hip_atomic_store(&buf[(size_t)(baserow + node)*DD + n], acc2[r],
                                       __ATOMIC_RELAXED, __HIP_MEMORY_SCOPE_AGENT);
            }
            // ---- check B: rides the store window ----
            if (havN && !padN && !ok) {
                VERIFY4(u, ok);
                if (!ok) LOAD4(srcN, u);
            }
        }

        // ---- phase B: spin (sc1) only on genuine still-pending parents ----
        if (havN) {
            if (!padN) {
                while (!ok) {
                    VERIFY4(u, ok);
                    if (!ok) { __builtin_amdgcn_s_sleep(1); LOAD4(srcN, u); }
                }
            }
            WRITE_FRAG1(axn, u);
        }

        __syncthreads();
        unsigned short* t2 = axc; axc = axn; axn = t2;
    }
}

extern "C" void kernel_launch(void* const* d_in, const int* in_sizes, int n_in,
                              void* d_out, int out_size, void* d_ws, size_t ws_size,
                              hipStream_t stream) {
    const float* root  = (const float*)d_in[0];   // (1024, 128)
    const float* W1    = (const float*)d_in[1];   // (5, 256, 256)
    const float* b1    = (const float*)d_in[2];   // (5, 256)
    const float* W2    = (const float*)d_in[3];   // (5, 256, 128)
    const float* b2    = (const float*)d_in[4];   // (5, 128)
    const float* slots = (const float*)d_in[5];   // (256, 128)
    const int*   par   = (const int*)d_in[6];     // (131072, 2)
    const int*   typ   = (const int*)d_in[7];     // (131072,)
    float* out = (float*)d_out;                   // (132096, 128)

    unsigned short* W1F   = (unsigned short*)d_ws;          // 327680 shorts
    unsigned short* W2F   = W1F + 5*16*8*64*8;              // 163840 shorts
    unsigned short* order = W2F + 5*8*8*64*8;               // 64*2528 shorts

    // prep dispatch (order, weights, roots, SENTINEL fill) -- plain cached stores
    prep_all<<<LL + 240 + 32 + 4096, 256, 0, stream>>>(root, W1, W2, typ, par, out,
                                                       W1F, W2F, order);

    // persistent dataflow sweep
    void* args[] = { (void*)&W1F, (void*)&W2F, (void*)&b1, (void*)&b2,
                     (void*)&slots, (void*)&par, (void*)&typ, (void*)&order,
                     (void*)&out };
    hipLaunchCooperativeKernel((const void*)persist_mfma, dim3(CH), dim3(512),
                               args, 0, stream);
}

// Round 22
// 196.034 us; speedup vs baseline: 1.5530x; 1.0903x over previous
//
#include <hip/hip_runtime.h>
#include <math.h>

#define DD 128          // node embedding dim
#define RR 1024         // root nodes
#define TT 4            // trunk types; encoder TT is the output autoencoder
#define LL 64           // levels
#define MM 2048         // nodes per level
#define NBK 16          // nodes per chunk (one MFMA M-tile)
#define GT 37           // chunk slots per trunk type
#define GO 10           // chunk slots for output type
#define CCAP (4*GT + GO)       // 158 global chunk slots per level == #WGs
#define PAD16 (CCAP*NBK)       // 2528 order slots per level
#define CH CCAP
#define SENTU 0xFFFFFFFFu      // NaN sentinel; MLP outputs are finite -> never equal

typedef __attribute__((ext_vector_type(8))) short short8v;
typedef __attribute__((ext_vector_type(4))) float f32x4;
typedef unsigned long long ull;

static __device__ __forceinline__ unsigned short f2bf(float f) {
    unsigned u = __float_as_uint(f);
    unsigned r = (u + 0x7fffu + ((u >> 16) & 1u)) >> 16;   // RNE
    return (unsigned short)r;
}

// A&S 7.1.26 erf (|err| < 1.5e-7), branchless
static __device__ __forceinline__ float gelu_f(float h) {
    float x  = h * 0.70710678118654752f;
    float ax = fabsf(x);
    float t  = __builtin_amdgcn_rcpf(fmaf(0.3275911f, ax, 1.0f));
    float p  = fmaf(t, 1.061405429f, -1.453152027f);
    p = fmaf(p, t, 1.421413741f);
    p = fmaf(p, t, -0.284496736f);
    p = fmaf(p, t, 0.254829592f);
    p = p * t;
    float er = 1.0f - p * __expf(-ax * ax);
    er = copysignf(er, x);
    return 0.5f * h * (1.0f + er);
}

// ---------------------------------------------------------------------------
// Fused prep (r19/r21): order build | weight convert | root copy | sentinel
// fill. All PLAIN cached stores -- published by the dispatch boundary.
// ---------------------------------------------------------------------------
__global__ __launch_bounds__(256) void prep_all(
    const float* __restrict__ root, const float* __restrict__ W1,
    const float* __restrict__ W2, const int* __restrict__ types,
    const int* __restrict__ par,
    float* __restrict__ buf,
    unsigned short* __restrict__ W1F, unsigned short* __restrict__ W2F,
    unsigned short* __restrict__ order)
{
    int bid = blockIdx.x, tid = threadIdx.x;
    if (bid < LL) {
        int l = bid;
        __shared__ int cnt[10], cur[10];
        if (tid < 10) cnt[tid] = 0;
        __syncthreads();
        for (int s = tid; s < PAD16; s += 256) order[l*PAD16 + s] = 0xFFFFu;
        int thr = RR + (l-1)*MM;    // parents >= thr come from level l-1
        for (int m = tid; m < MM; m += 256) {
            int gi = l*MM + m;
            int t = types[gi];
            int e = (t >= TT) ? TT : t;
            int p0 = par[2*gi];
            bool rec = (p0 >= RR) && (p0 >= thr);
            if (t < TT) {
                int p1 = par[2*gi + 1];
                rec = rec || ((p1 >= RR) && (p1 >= thr));
            }
            atomicAdd(&cnt[e*2 + (rec ? 1 : 0)], 1);
        }
        __syncthreads();
        if (tid == 0) {
            for (int e = 0; e < 5; e++) {
                int base = ((e < 4) ? e*GT : 4*GT) * NBK;
                int s = cnt[e*2];
                cur[e*2]     = base;
                cur[e*2 + 1] = base + ((s + NBK - 1)/NBK)*NBK;
            }
        }
        __syncthreads();
        for (int m = tid; m < MM; m += 256) {
            int gi = l*MM + m;
            int t = types[gi];
            int e = (t >= TT) ? TT : t;
            int p0 = par[2*gi];
            bool rec = (p0 >= RR) && (p0 >= thr);
            if (t < TT) {
                int p1 = par[2*gi + 1];
                rec = rec || ((p1 >= RR) && (p1 >= thr));
            }
            int pos = atomicAdd(&cur[e*2 + (rec ? 1 : 0)], 1);
            order[l*PAD16 + pos] = (unsigned short)m;
        }
    } else if (bid < LL + 240) {
        int t0 = (bid - LL)*256 + tid;
        if (t0 < 5*16*8*64) {
            int lane = t0 & 63;
            int kk = (t0 >> 6) & 7;
            int nt = (t0 >> 9) & 15;
            int e  = t0 >> 13;
            int n  = nt*16 + (lane & 15);
            int k0 = kk*32 + (lane >> 4)*8;
            unsigned short v[8];
            #pragma unroll
            for (int j = 0; j < 8; j++) v[j] = f2bf(W1[(e*256 + k0 + j)*256 + n]);
            *(short8v*)&W1F[t0*8] = *(short8v*)v;
        } else {
            int t = t0 - 5*16*8*64;   // < 20480
            int lane = t & 63;
            int kk = (t >> 6) & 7;
            int nt = (t >> 9) & 7;
            int e  = t >> 12;
            int n  = nt*16 + (lane & 15);
            int k0 = kk*32 + (lane >> 4)*8;
            unsigned short v[8];
            #pragma unroll
            for (int j = 0; j < 8; j++) v[j] = f2bf(W2[(e*256 + k0 + j)*128 + n]);
            *(short8v*)&W2F[t*8] = *(short8v*)v;
        }
    } else if (bid < LL + 240 + 32) {
        int idx = (bid - (LL + 240))*256 + tid;   // 0..8191
        const f32x4* r4 = (const f32x4*)root;
        f32x4* o4 = (f32x4*)buf;
        #pragma unroll
        for (int q = 0; q < 4; q++) o4[idx*4 + q] = r4[idx*4 + q];
    } else {
        // sentinel fill: rows RR..N-1, 16 floats per thread
        int idx = (bid - (LL + 240 + 32))*256 + tid;   // 0 .. 1048575
        float s = __uint_as_float(SENTU);
        f32x4 sv = (f32x4){s, s, s, s};
        f32x4* p = (f32x4*)(buf + (size_t)RR*DD) + (size_t)idx*4;
        p[0] = sv; p[1] = sv; p[2] = sv; p[3] = sv;
    }
}

// ---------------------------------------------------------------------------
// Persistent dataflow kernel (r21 + early frag writes), REGULAR launch:
// 158 blocks <= 256 CUs => all blocks hardware-resident at dispatch, no
// cooperative machinery needed (kernel uses only its own sentinel-poll sync).
// ---------------------------------------------------------------------------
__global__ __launch_bounds__(512, 2) void persist_mfma(
    const unsigned short* __restrict__ W1F, const unsigned short* __restrict__ W2F,
    const float* __restrict__ b1, const float* __restrict__ b2,
    const float* __restrict__ slots, const int* __restrict__ par,
    const int* __restrict__ types, const unsigned short* __restrict__ order,
    float* __restrict__ buf)
{
    __shared__ int4 descs[LL][NBK];            // {node, p0, p1(~slot if out), etype}
    __shared__ int ech[LL];
    __shared__ unsigned short axFA[8*64*8];    // A-frags of x, 8 KB
    __shared__ unsigned short axFB[8*64*8];    // double buffer, 8 KB
    __shared__ unsigned short hxF[8*64*8];     // A-frags of h, 8 KB

    int tid = threadIdx.x;
    int wg  = blockIdx.x;
    int e_wg = (wg < 4*GT) ? (wg / GT) : TT;   // static encoder type of this WG

    int w  = tid >> 6;    // wave 0..7
    int lq = tid & 63;    // lane
    // 512-thread gather: each thread owns 32 B (8 floats) = one A-fragment
    int m_own    = tid >> 5;          // node 0..15
    int hs       = tid & 31;          // 8-float slot 0..31
    int kk_own   = hs >> 2;           // fragment kk
    int lane_own = m_own + 16*(hs & 3);
    int seg16    = hs >> 1;           // 16-float segment 0..15
    int half8    = hs & 1;            // which 8-float half

    // ---- preload weight B-fragments + biases into registers ----
    short8v w1r0[8], w1r1[8], w2r[8];
    #pragma unroll
    for (int kk = 0; kk < 8; kk++) {
        w1r0[kk] = *(const short8v*)&W1F[(((e_wg*16 + 2*w + 0)*8 + kk)*64 + lq)*8];
        w1r1[kk] = *(const short8v*)&W1F[(((e_wg*16 + 2*w + 1)*8 + kk)*64 + lq)*8];
        w2r[kk]  = *(const short8v*)&W2F[(((e_wg*8  + w)*8 + kk)*64 + lq)*8];
    }
    float b1v0 = b1[e_wg*256 + (2*w + 0)*16 + (lq & 15)];
    float b1v1 = b1[e_wg*256 + (2*w + 1)*16 + (lq & 15)];
    float b2v  = b2[e_wg*128 + w*16 + (lq & 15)];

    // ---- prologue: resolve all levels' descriptors ----
    for (int i = tid; i < LL*NBK; i += 512) {
        int l = i >> 4, s = i & 15;
        unsigned short o = order[l*PAD16 + wg*NBK + s];
        int4 d;
        if (o == 0xFFFFu) {
            d = make_int4(-1, 0, 0, -1);
        } else {
            int gi = l*MM + (int)o;
            int t = types[gi];
            int e = (t >= TT) ? TT : t;
            int p0 = par[2*gi];
            int p1 = (t >= TT) ? ~(t - TT) : par[2*gi + 1];
            d = make_int4((int)o, p0, p1, e);
        }
        descs[l][s] = d;
    }
    __syncthreads();
    for (int i = tid; i < LL; i += 512) ech[i] = descs[i][0].w;
    __syncthreads();

    #define RESOLVE_SRC(l1, S, P) {                                            \
        int4 d_ = descs[l1][m_own];                                            \
        if (d_.x < 0) { P = true; S = nullptr; }                               \
        else {                                                                 \
            P = false;                                                         \
            if (seg16 < 8)     S = buf + (size_t)d_.y*DD + seg16*16 + half8*8; \
            else if (d_.z < 0) S = slots + (size_t)(~d_.z)*DD + (seg16-8)*16 + half8*8; \
            else               S = buf + (size_t)d_.z*DD + (seg16-8)*16 + half8*8; \
        } }

    #define LOAD4P(S, U) {                                                     \
        const ull* s8_ = (const ull*)(S);                                      \
        _Pragma("unroll")                                                      \
        for (int q_ = 0; q_ < 4; q_++) U[q_] = s8_[q_];                        \
    }
    #define LOAD4(S, U) {                                                      \
        const ull* s8_ = (const ull*)(S);                                      \
        _Pragma("unroll")                                                      \
        for (int q_ = 0; q_ < 4; q_++)                                         \
            U[q_] = __hip_atomic_load(&s8_[q_], __ATOMIC_RELAXED,              \
                                      __HIP_MEMORY_SCOPE_AGENT);               \
    }
    #define VERIFY4(U, OK) { OK = true;                                        \
        _Pragma("unroll")                                                      \
        for (int q_ = 0; q_ < 4; q_++) {                                       \
            unsigned lo_ = (unsigned)U[q_], hi_ = (unsigned)(U[q_] >> 32);     \
            OK = OK && (lo_ != SENTU) && (hi_ != SENTU);                       \
        } }
    #define WRITE_FRAG1(AXT, U) {                                              \
        unsigned short t_[8];                                                  \
        _Pragma("unroll")                                                      \
        for (int q_ = 0; q_ < 4; q_++) {                                       \
            t_[2*q_]   = f2bf(__uint_as_float((unsigned)U[q_]));               \
            t_[2*q_+1] = f2bf(__uint_as_float((unsigned)(U[q_] >> 32)));       \
        }                                                                      \
        *(short8v*)&AXT[(kk_own*64 + lane_own)*8] = *(short8v*)t_;             \
    }

    // ---- level-0 gather (roots/slots: written by prep, always clean) ----
    {
        const float* src; bool pad;
        RESOLVE_SRC(0, src, pad);
        ull u0[4];
        if (!pad) {
            LOAD4P(src, u0);
            bool ok; VERIFY4(u0, ok);
            while (!ok) { __builtin_amdgcn_s_sleep(1); LOAD4(src, u0); VERIFY4(u0, ok); }
        } else {
            #pragma unroll
            for (int q = 0; q < 4; q++) u0[q] = 0ull;
        }
        WRITE_FRAG1(axFA, u0);
    }
    __syncthreads();

    unsigned short* axc = axFA;
    unsigned short* axn = axFB;

    for (int l = 0; l < LL; l++) {
        bool havN = (l + 1 < LL);

        // ---- phase A: issue PLAIN loads for level l+1 parents ----
        const float* srcN = nullptr; bool padN = true; bool ok = true; bool wrote = false;
        ull u[4];
        #pragma unroll
        for (int q = 0; q < 4; q++) u[q] = 0ull;
        if (havN) {
            RESOLVE_SRC(l+1, srcN, padN);
            if (!padN) { LOAD4P(srcN, u); ok = false; }
        }
        __builtin_amdgcn_sched_barrier(0);   // pin: loads issued before compute

        int e = ech[l];
        if (e >= 0) {
            // ---- layer 1: H = GELU(X @ W1 + b1), 4 chains of depth 2 ----
            f32x4 z4 = (f32x4){0.f,0.f,0.f,0.f};
            f32x4 a00 = (f32x4){b1v0,b1v0,b1v0,b1v0}, a01 = z4, a02 = z4, a03 = z4;
            f32x4 a10 = (f32x4){b1v1,b1v1,b1v1,b1v1}, a11 = z4, a12 = z4, a13 = z4;
            {
                const short8v* Ab = (const short8v*)axc;
                short8v a0 = Ab[0*64+lq], a1 = Ab[1*64+lq], a2 = Ab[2*64+lq], a3 = Ab[3*64+lq];
                short8v a4 = Ab[4*64+lq], a5 = Ab[5*64+lq], a6 = Ab[6*64+lq], a7 = Ab[7*64+lq];
                a00 = __builtin_amdgcn_mfma_f32_16x16x32_bf16(a0, w1r0[0], a00, 0,0,0);
                a01 = __builtin_amdgcn_mfma_f32_16x16x32_bf16(a2, w1r0[2], a01, 0,0,0);
                a02 = __builtin_amdgcn_mfma_f32_16x16x32_bf16(a4, w1r0[4], a02, 0,0,0);
                a03 = __builtin_amdgcn_mfma_f32_16x16x32_bf16(a6, w1r0[6], a03, 0,0,0);
                a10 = __builtin_amdgcn_mfma_f32_16x16x32_bf16(a0, w1r1[0], a10, 0,0,0);
                a11 = __builtin_amdgcn_mfma_f32_16x16x32_bf16(a2, w1r1[2], a11, 0,0,0);
                a12 = __builtin_amdgcn_mfma_f32_16x16x32_bf16(a4, w1r1[4], a12, 0,0,0);
                a13 = __builtin_amdgcn_mfma_f32_16x16x32_bf16(a6, w1r1[6], a13, 0,0,0);
                a00 = __builtin_amdgcn_mfma_f32_16x16x32_bf16(a1, w1r0[1], a00, 0,0,0);
                a01 = __builtin_amdgcn_mfma_f32_16x16x32_bf16(a3, w1r0[3], a01, 0,0,0);
                a02 = __builtin_amdgcn_mfma_f32_16x16x32_bf16(a5, w1r0[5], a02, 0,0,0);
                a03 = __builtin_amdgcn_mfma_f32_16x16x32_bf16(a7, w1r0[7], a03, 0,0,0);
                a10 = __builtin_amdgcn_mfma_f32_16x16x32_bf16(a1, w1r1[1], a10, 0,0,0);
                a11 = __builtin_amdgcn_mfma_f32_16x16x32_bf16(a3, w1r1[3], a11, 0,0,0);
                a12 = __builtin_amdgcn_mfma_f32_16x16x32_bf16(a5, w1r1[5], a12, 0,0,0);
                a13 = __builtin_amdgcn_mfma_f32_16x16x32_bf16(a7, w1r1[7], a13, 0,0,0);
            }
            f32x4 acc0 = (a00 + a01) + (a02 + a03);
            f32x4 acc1 = (a10 + a11) + (a12 + a13);
            // ---- check A: arrived? write frags now (axn free); else reissue ----
            if (havN && !padN && !ok) {
                VERIFY4(u, ok);
                if (ok) { WRITE_FRAG1(axn, u); wrote = true; }
                else    { LOAD4(srcN, u); }
            }
            __builtin_amdgcn_sched_barrier(0);

            // GELU + scatter H into A-frag LDS (nt = 2w+c, c in {0,1})
            #pragma unroll
            for (int c = 0; c < 2; c++) {
                int nh = (2*w + c)*16 + (lq & 15);
                int kk2 = nh >> 5;
                int jj  = nh & 7;
                int lhi = 16*((nh >> 3) & 3);
                #pragma unroll
                for (int r = 0; r < 4; r++) {
                    int m = (lq >> 4)*4 + r;
                    float h = (c == 0) ? acc0[r] : acc1[r];
                    hxF[(kk2*64 + (m + lhi))*8 + jj] = f2bf(gelu_f(h));
                }
            }
            __syncthreads();

            // ---- layer 2: OUT = H @ W2 + b2, 4 chains of depth 2 ----
            f32x4 z4b = (f32x4){0.f,0.f,0.f,0.f};
            f32x4 c0 = (f32x4){b2v,b2v,b2v,b2v}, c1 = z4b, c2 = z4b, c3 = z4b;
            {
                const short8v* Hb = (const short8v*)hxF;
                short8v h0 = Hb[0*64+lq], h1 = Hb[1*64+lq], h2 = Hb[2*64+lq], h3 = Hb[3*64+lq];
                short8v h4 = Hb[4*64+lq], h5 = Hb[5*64+lq], h6 = Hb[6*64+lq], h7 = Hb[7*64+lq];
                c0 = __builtin_amdgcn_mfma_f32_16x16x32_bf16(h0, w2r[0], c0, 0,0,0);
                c1 = __builtin_amdgcn_mfma_f32_16x16x32_bf16(h2, w2r[2], c1, 0,0,0);
                c2 = __builtin_amdgcn_mfma_f32_16x16x32_bf16(h4, w2r[4], c2, 0,0,0);
                c3 = __builtin_amdgcn_mfma_f32_16x16x32_bf16(h6, w2r[6], c3, 0,0,0);
                c0 = __builtin_amdgcn_mfma_f32_16x16x32_bf16(h1, w2r[1], c0, 0,0,0);
                c1 = __builtin_amdgcn_mfma_f32_16x16x32_bf16(h3, w2r[3], c1, 0,0,0);
                c2 = __builtin_amdgcn_mfma_f32_16x16x32_bf16(h5, w2r[5], c2, 0,0,0);
                c3 = __builtin_amdgcn_mfma_f32_16x16x32_bf16(h7, w2r[7], c3, 0,0,0);
            }
            f32x4 acc2 = (c0 + c1) + (c2 + c3);
            // result rows: sc1 write-through; fire-and-forget
            int baserow = RR + l*MM;
            int n = w*16 + (lq & 15);
            #pragma unroll
            for (int r = 0; r < 4; r++) {
                int m = (lq >> 4)*4 + r;
                int node = descs[l][m].x;
                if (node >= 0)
                    __hip_atomic_store(&buf[(size_t)(baserow + node)*DD + n], acc2[r],
                                       __ATOMIC_RELAXED, __HIP_MEMORY_SCOPE_AGENT);
            }
            // ---- check B: rides the store window; write frags if arrived ----
            if (havN && !padN && !ok) {
                VERIFY4(u, ok);
                if (ok) { WRITE_FRAG1(axn, u); wrote = true; }
                else    { LOAD4(srcN, u); }
            }
        }

        // ---- phase B: stragglers spin (sc1); everyone ensures frag written ----
        if (havN) {
            if (padN) {
                if (!wrote) { WRITE_FRAG1(axn, u); }   // zeros
            } else if (!wrote) {
                if (ok) {
                    WRITE_FRAG1(axn, u);
                } else {
                    while (!ok) {
                        VERIFY4(u, ok);
                        if (!ok) { __builtin_amdgcn_s_sleep(1); LOAD4(srcN, u); }
                    }
                    WRITE_FRAG1(axn, u);
                }
            }
        }

        __syncthreads();
        unsigned short* t2 = axc; axc = axn; axn = t2;
    }
}

extern "C" void kernel_launch(void* const* d_in, const int* in_sizes, int n_in,
                              void* d_out, int out_size, void* d_ws, size_t ws_size,
                              hipStream_t stream) {
    const float* root  = (const float*)d_in[0];   // (1024, 128)
    const float* W1    = (const float*)d_in[1];   // (5, 256, 256)
    const float* b1    = (const float*)d_in[2];   // (5, 256)
    const float* W2    = (const float*)d_in[3];   // (5, 256, 128)
    const float* b2    = (const float*)d_in[4];   // (5, 128)
    const float* slots = (const float*)d_in[5];   // (256, 128)
    const int*   par   = (const int*)d_in[6];     // (131072, 2)
    const int*   typ   = (const int*)d_in[7];     // (131072,)
    float* out = (float*)d_out;                   // (132096, 128)

    unsigned short* W1F   = (unsigned short*)d_ws;          // 327680 shorts
    unsigned short* W2F   = W1F + 5*16*8*64*8;              // 163840 shorts
    unsigned short* order = W2F + 5*8*8*64*8;               // 64*2528 shorts

    // prep dispatch (order, weights, roots, SENTINEL fill) -- plain cached stores
    prep_all<<<LL + 240 + 32 + 4096, 256, 0, stream>>>(root, W1, W2, typ, par, out,
                                                       W1F, W2F, order);

    // persistent dataflow sweep -- REGULAR launch: 158 blocks <= 256 CUs,
    // all hardware-resident at dispatch; kernel uses only sentinel-poll sync.
    persist_mfma<<<CH, 512, 0, stream>>>(W1F, W2F, b1, b2, slots, par, typ,
                                         order, out);
}